// Round 6
// baseline (63374.084 us; speedup 1.0000x reference)
//
#include <hip/hip_runtime.h>

#define TSTEPS 8192
#define HDIM   1024
#define NLAYER 4
#define NB     256          // 4 groups x 64 blocks, 1 block/CU
#define NT     1024         // 16 waves/block
#define GB     64           // blocks per group (per layer)
#define EPB    16           // h elements per block (1 per wave)
#define RING   8            // ring-buffer depth per layer boundary

typedef float    f32x4 __attribute__((ext_vector_type(4)));
typedef unsigned u32x4 __attribute__((ext_vector_type(4)));

struct GruParams {
  const float* xs;
  const float* Wih[NLAYER];
  const float* Whh[NLAYER];
  const float* bias[NLAYER];
  const float* bn[NLAYER];
  float* out;                   // d_out (written by group 3)
  int*   tags;                  // ws: NB consume-tags (throttle only)
  unsigned long long* hbp;      // ws: NLAYER*2*HDIM (value,epoch) pairs
  unsigned long long* ringp;    // ws: 3*RING*HDIM (value,epoch) pairs
};

__device__ __forceinline__ float sigmoidf_(float x) {
  return 1.0f / (1.0f + __expf(-x));
}
__device__ __forceinline__ float tanhf_(float x) {
  const float e = __expf(2.0f * x);
  return 1.0f - 2.0f / (e + 1.0f);
}
__device__ __forceinline__ float rfl_(float x) {
  return __int_as_float(__builtin_amdgcn_readfirstlane(__float_as_int(x)));
}

// Spin-gather 4 (value,epoch) pairs at pp[0..3] until all epochs == e (sc1,
// IF-coherent); write the 4 values to dst[0..3]. 8B pair stores are atomic,
// so a stale epoch simply means "retry" — no tearing.
__device__ __forceinline__ void gather4_(const unsigned long long* pp,
                                         unsigned e, float* dst) {
  u32x4 A, B;
  for (;;) {
    asm volatile(
        "global_load_dwordx4 %0, %2, off sc1\n\t"
        "global_load_dwordx4 %1, %3, off sc1\n\t"
        "s_waitcnt vmcnt(0)"
        : "=&v"(A), "=&v"(B)
        : "v"(pp), "v"(pp + 2)
        : "memory");
    const bool ok = (A.y == e) & (A.w == e) & (B.y == e) & (B.w == e);
    if (__all(ok)) break;
  }
  dst[0] = __uint_as_float(A.x);
  dst[1] = __uint_as_float(A.z);
  dst[2] = __uint_as_float(B.x);
  dst[3] = __uint_as_float(B.z);
}

__device__ __forceinline__ void store_pair_(unsigned long long* p,
                                            float v, unsigned e) {
  const unsigned long long pk =
      ((unsigned long long)e << 32) | (unsigned long long)__float_as_uint(v);
  asm volatile("global_store_dwordx2 %0, %1, off sc1"
               :: "v"(p), "v"(pk) : "memory");
}

// Layer-pipelined persistent GRU, epoch-tagged dataflow.
// Group g = layer g. Wave w owns h element j = m*16+w; its 6 weight rows
// (96 floats) are pinned in VGPRs: amdgpu_waves_per_eu(4,4) gives the
// 128-VGPR budget (16 waves/block, 1 block/CU -> 4 waves/EU), and the empty
// asm "+v" pass makes the loaded values non-rematerializable so the compiler
// cannot re-read them from memory inside the t-loop.
__global__ __attribute__((amdgpu_flat_work_group_size(NT, NT),
                          amdgpu_waves_per_eu(4, 4)))
void gru_pipe(GruParams p) {
  __shared__ float xst[2][HDIM];
  __shared__ float hst[2][HDIM];
  const int tid  = threadIdx.x;
  const int lane = tid & 63;
  const int wave = tid >> 6;
  const int blk  = blockIdx.x;
  const int g    = blk >> 6;
  const int m    = blk & 63;
  const int j    = m * EPB + wave;

  // ---- weights: 6 rows of 1024 for element j -> 24 f32x4 = 96 VGPRs ----
  const float* Wih = p.Wih[g];
  const float* Whh = p.Whh[g];
  f32x4 w4[24];
#pragma unroll
  for (int dd = 0; dd < 6; ++dd) {
    const float* W = (dd < 3) ? Wih : Whh;
    const int gate = (dd < 3) ? dd : dd - 3;
    const float* src = W + ((size_t)gate * HDIM + j) * HDIM + lane * 4;
#pragma unroll
    for (int i = 0; i < 4; ++i)
      w4[dd * 4 + i] = *reinterpret_cast<const f32x4*>(src + i * 256);
  }
#pragma unroll
  for (int k = 0; k < 24; ++k)
    asm volatile("" : "+v"(w4[k]));   // pin: not rematerializable

  const float bb0 = rfl_(p.bias[g][j]);
  const float bb1 = rfl_(p.bias[g][HDIM + j]);
  const float bb2 = rfl_(p.bias[g][2 * HDIM + j]);
  const float bnv = rfl_(p.bn[g][j]);
  float hreg = 0.f;

  unsigned long long* hb = p.hbp + (size_t)g * 2 * HDIM;
  const unsigned long long* ring_in  = p.ringp + (size_t)(g - 1) * RING * HDIM;
  unsigned long long*       ring_out = p.ringp + (size_t)g * RING * HDIM;
  const int* dwnp = p.tags + (g + 1) * GB + lane;   // valid when g<3

  for (int t = 0; t < TSTEPS; ++t) {
    const int ls = t & 1;       // LDS buffer for this tick
    const int base = (wave & 3) * 256 + lane * 4;

    if (wave < 4) {
      // ---- h_{t-1}: pairs in slot t&1 carry epoch t ----
      if (t > 0) {
        gather4_(hb + (size_t)(t & 1) * HDIM + base, (unsigned)t,
                 &hst[ls][base]);
      } else {
        const f32x4 z4 = {0.f, 0.f, 0.f, 0.f};
        *reinterpret_cast<f32x4*>(&hst[ls][base]) = z4;
      }
    } else if (wave < 8) {
      // ---- x_t: ring slot t&7 carries epoch t+1 (layer 0: plain load) ----
      if (g > 0) {
        gather4_(ring_in + (size_t)(t & (RING - 1)) * HDIM + base,
                 (unsigned)(t + 1), &xst[ls][base]);
      } else {
        *reinterpret_cast<f32x4*>(&xst[ls][base]) =
            *reinterpret_cast<const f32x4*>(p.xs + (size_t)t * HDIM + base);
      }
    } else if (wave == 15) {
      // ---- ring-overwrite throttle (off critical path; rarely binds) ----
      if (g < 3 && t >= RING) {
        for (;;) {
          const int v = __hip_atomic_load(dwnp, __ATOMIC_RELAXED,
                                          __HIP_MEMORY_SCOPE_AGENT);
          if (__all(v >= t - (RING - 1))) break;
        }
      }
    }
    __syncthreads();

    // consume-tag: inputs of tick t are now in LDS; upstream may overwrite.
    if (tid == 0)
      __hip_atomic_store(&p.tags[blk], t + 1,
                         __ATOMIC_RELAXED, __HIP_MEMORY_SCOPE_AGENT);

    // ---- 6 dot-1024s (3 ih + 3 hh) ----
    float a0 = 0.f, a1 = 0.f, a2 = 0.f, a3 = 0.f, a4 = 0.f, a5 = 0.f;
#pragma unroll
    for (int i = 0; i < 4; ++i) {
      const f32x4 xc = *reinterpret_cast<const f32x4*>(&xst[ls][lane * 4 + i * 256]);
      const f32x4 hc = *reinterpret_cast<const f32x4*>(&hst[ls][lane * 4 + i * 256]);
#pragma unroll
      for (int q = 0; q < 4; ++q) {
        const float xq = xc[q], hq = hc[q];
        a0 = fmaf(w4[0 * 4 + i][q], xq, a0);
        a1 = fmaf(w4[1 * 4 + i][q], xq, a1);
        a2 = fmaf(w4[2 * 4 + i][q], xq, a2);
        a3 = fmaf(w4[3 * 4 + i][q], hq, a3);
        a4 = fmaf(w4[4 * 4 + i][q], hq, a4);
        a5 = fmaf(w4[5 * 4 + i][q], hq, a5);
      }
    }
#pragma unroll
    for (int off = 32; off > 0; off >>= 1) {
      a0 += __shfl_xor(a0, off, 64);
      a1 += __shfl_xor(a1, off, 64);
      a2 += __shfl_xor(a2, off, 64);
      a3 += __shfl_xor(a3, off, 64);
      a4 += __shfl_xor(a4, off, 64);
      a5 += __shfl_xor(a5, off, 64);
    }

    // ---- gates; publish epoch-tagged h + ring/out ----
    const float r = sigmoidf_(a0 + bb0 + a3);
    const float z = sigmoidf_(a1 + bb1 + a4);
    const float n = tanhf_(a2 + bb2 + r * (a5 + bnv));
    const float hnew = n + z * (hreg - n);
    hreg = hnew;
    if (lane == 0) {
      store_pair_(&hb[(size_t)((t + 1) & 1) * HDIM + j], hnew,
                  (unsigned)(t + 1));
      if (g < 3)
        store_pair_(&ring_out[(size_t)(t & (RING - 1)) * HDIM + j], hnew,
                    (unsigned)(t + 1));
      else
        __hip_atomic_store(&p.out[(size_t)t * HDIM + j], hnew,
                           __ATOMIC_RELAXED, __HIP_MEMORY_SCOPE_AGENT);
    }
    // no end-of-tick barrier: LDS is double-buffered; epoch checks make
    // early overwrites impossible (see R5 analysis).
  }
}

extern "C" void kernel_launch(void* const* d_in, const int* in_sizes, int n_in,
                              void* d_out, int out_size, void* d_ws, size_t ws_size,
                              hipStream_t stream) {
  GruParams p;
  p.xs = (const float*)d_in[0];
  for (int l = 0; l < NLAYER; ++l) {
    p.Wih[l]  = (const float*)d_in[1 + 4 * l];
    p.Whh[l]  = (const float*)d_in[2 + 4 * l];
    p.bias[l] = (const float*)d_in[3 + 4 * l];
    p.bn[l]   = (const float*)d_in[4 + 4 * l];
  }
  char* ws = (char*)d_ws;
  size_t off = 0;
  p.tags = (int*)(ws + off);
  off += (size_t)NB * sizeof(int);
  off = (off + 255) & ~(size_t)255;
  p.hbp = (unsigned long long*)(ws + off);
  const size_t hbp_bytes = (size_t)NLAYER * 2 * HDIM * 8;
  off += hbp_bytes;
  p.ringp = (unsigned long long*)(ws + off);
  const size_t ring_bytes = (size_t)3 * RING * HDIM * 8;
  off += ring_bytes;
  p.out = (float*)d_out;

  // clear tags + all epoch-bearing pairs (replay safety: epochs restart at 1)
  (void)hipMemsetAsync(p.tags, 0, (size_t)NB * sizeof(int), stream);
  (void)hipMemsetAsync(p.hbp, 0, hbp_bytes, stream);
  (void)hipMemsetAsync(p.ringp, 0, ring_bytes, stream);
  gru_pipe<<<dim3(NB), dim3(NT), 0, stream>>>(p);
}

// Round 7
// 44027.972 us; speedup vs baseline: 1.4394x; 1.4394x over previous
//
#include <hip/hip_runtime.h>

#define TSTEPS 8192
#define HDIM   1024
#define NLAYER 4
#define NB     256          // 4 groups x 64 blocks, 1 block/CU (LDS-forced)
#define NT     512          // 8 waves/block
#define GB     64           // blocks per group (per layer)
#define EPB    16           // h elements per block
#define RING   8            // ring-buffer depth per layer boundary

typedef float f32x4 __attribute__((ext_vector_type(4)));

struct GruParams {
  const float* xs;
  const float* Wih[NLAYER];
  const float* Whh[NLAYER];
  const float* bias[NLAYER];
  const float* bn[NLAYER];
  float* out;        // d_out (written by group 3)
  int*   tags;       // ws: NB progress tags
  float* hbuf;       // ws: NLAYER * 2 * HDIM (double-buffered h per group)
  float* ring;       // ws: 3 * RING * HDIM (layer-boundary rings)
};

__device__ __forceinline__ float sigmoidf_(float x) {
  return 1.0f / (1.0f + __expf(-x));
}
__device__ __forceinline__ float tanhf_(float x) {
  const float e = __expf(2.0f * x);
  return 1.0f - 2.0f / (e + 1.0f);
}
__device__ __forceinline__ float rfl_(float x) {
  return __int_as_float(__builtin_amdgcn_readfirstlane(__float_as_int(x)));
}

// 4x coherent (sc1, IF-scope) dwordx4 gather of a 4KB row -> LDS staging.
__device__ __forceinline__ void gather_row_(const float* row, float* lds,
                                            int lane) {
  const float* r0 = row + lane * 4;
  f32x4 a, b, c, d;
  asm volatile(
      "global_load_dwordx4 %0, %4, off sc1\n\t"
      "global_load_dwordx4 %1, %5, off sc1\n\t"
      "global_load_dwordx4 %2, %6, off sc1\n\t"
      "global_load_dwordx4 %3, %7, off sc1\n\t"
      "s_waitcnt vmcnt(0)"
      : "=&v"(a), "=&v"(b), "=&v"(c), "=&v"(d)
      : "v"(r0), "v"(r0 + 256), "v"(r0 + 512), "v"(r0 + 768)
      : "memory");
  *reinterpret_cast<f32x4*>(&lds[lane * 4 +   0]) = a;
  *reinterpret_cast<f32x4*>(&lds[lane * 4 + 256]) = b;
  *reinterpret_cast<f32x4*>(&lds[lane * 4 + 512]) = c;
  *reinterpret_cast<f32x4*>(&lds[lane * 4 + 768]) = d;
}

// Layer-pipelined persistent GRU, R4 tag sync, 192 weight floats/thread.
// The 84KB static LDS forces 1 block/CU -> 8 waves/CU -> 2 waves/SIMD ->
// 256-VGPR budget, making the weights genuinely register-resident.
__global__ __attribute__((amdgpu_flat_work_group_size(NT, NT),
                          amdgpu_waves_per_eu(2, 2)))
void gru_pipe(GruParams p) {
  __shared__ float xst[HDIM];
  __shared__ float hst[HDIM];
  __shared__ float pad[19456];   // occupancy clamp: total 84KB static LDS
  if ((size_t)p.out == 0) pad[threadIdx.x] = 0.f;   // unprovable; keeps pad

  const int tid  = threadIdx.x;
  const int lane = tid & 63;
  const int wave = tid >> 6;
  const int blk  = blockIdx.x;
  const int g    = blk >> 6;          // layer / group id
  const int m    = blk & 63;          // member within group
  const int j0   = m * EPB + wave * 2;  // this wave's two h elements

  // ---- weights: 12 rows of 1024 (2 elems x (3 ih + 3 hh)) -> 48 f32x4 ----
  const float* Wih = p.Wih[g];
  const float* Whh = p.Whh[g];
  f32x4 w4[48];
#pragma unroll
  for (int e = 0; e < 2; ++e) {
#pragma unroll
    for (int dd = 0; dd < 6; ++dd) {
      const float* W = (dd < 3) ? Wih : Whh;
      const int gate = (dd < 3) ? dd : dd - 3;
      const float* src = W + ((size_t)gate * HDIM + (j0 + e)) * HDIM + lane * 4;
#pragma unroll
      for (int i = 0; i < 4; ++i)
        w4[(e * 6 + dd) * 4 + i] = *reinterpret_cast<const f32x4*>(src + i * 256);
    }
  }
  const float bA0 = rfl_(p.bias[g][j0]);
  const float bA1 = rfl_(p.bias[g][HDIM + j0]);
  const float bA2 = rfl_(p.bias[g][2 * HDIM + j0]);
  const float bnA = rfl_(p.bn[g][j0]);
  const float bB0 = rfl_(p.bias[g][j0 + 1]);
  const float bB1 = rfl_(p.bias[g][HDIM + j0 + 1]);
  const float bB2 = rfl_(p.bias[g][2 * HDIM + j0 + 1]);
  const float bnB = rfl_(p.bn[g][j0 + 1]);
  float hregA = 0.f, hregB = 0.f;

  float* hb = p.hbuf + (size_t)g * 2 * HDIM;
  const float* ring_in  = p.ring + (size_t)(g - 1) * RING * HDIM;  // g>0
  float*       ring_out = p.ring + (size_t)g * RING * HDIM;        // g<3
  const int* ownp = p.tags + g * GB + lane;
  const int* upp  = (g > 0) ? (p.tags + (g - 1) * GB + lane) : ownp;
  const int* dwnp = (g < 3) ? (p.tags + (g + 1) * GB + lane) : ownp;

  for (int t = 0; t < TSTEPS; ++t) {
    // ---- wave 0: own-group h readiness + gather h -> LDS ----
    if (wave == 0) {
      if (t > 0) {
        for (;;) {
          const int v = __hip_atomic_load(ownp, __ATOMIC_RELAXED,
                                          __HIP_MEMORY_SCOPE_AGENT);
          if (__all(v >= t)) break;
        }
        gather_row_(hb + (size_t)(t & 1) * HDIM, hst, lane);
      } else {
        const f32x4 z4 = {0.f, 0.f, 0.f, 0.f};
#pragma unroll
        for (int i = 0; i < 4; ++i)
          *reinterpret_cast<f32x4*>(&hst[lane * 4 + i * 256]) = z4;
      }
    } else if (wave == 1) {
      // ---- wave 1: upstream row readiness + gather x -> LDS ----
      if (g > 0) {
        for (;;) {
          const int v = __hip_atomic_load(upp, __ATOMIC_RELAXED,
                                          __HIP_MEMORY_SCOPE_AGENT);
          if (__all(v >= t + 1)) break;
        }
        gather_row_(ring_in + (size_t)(t & (RING - 1)) * HDIM, xst, lane);
      } else {
        const float* xrow = p.xs + (size_t)t * HDIM + lane * 4;
#pragma unroll
        for (int i = 0; i < 4; ++i)
          *reinterpret_cast<f32x4*>(&xst[lane * 4 + i * 256]) =
              *reinterpret_cast<const f32x4*>(xrow + i * 256);
      }
    } else if (wave == 2) {
      // ---- wave 2: ring-overwrite throttle (off critical path) ----
      if (g < 3 && t >= RING) {
        for (;;) {
          const int v = __hip_atomic_load(dwnp, __ATOMIC_RELAXED,
                                          __HIP_MEMORY_SCOPE_AGENT);
          if (__all(v >= t - (RING - 1))) break;
        }
      }
    }
    __syncthreads();

    // ---- 12 dot-1024s (2 elems x 6), fully register-resident weights ----
    float A_ir = 0.f, A_iz = 0.f, A_in = 0.f, A_hr = 0.f, A_hz = 0.f, A_hn = 0.f;
    float B_ir = 0.f, B_iz = 0.f, B_in = 0.f, B_hr = 0.f, B_hz = 0.f, B_hn = 0.f;
#pragma unroll
    for (int i = 0; i < 4; ++i) {
      const f32x4 xc = *reinterpret_cast<const f32x4*>(&xst[lane * 4 + i * 256]);
      const f32x4 hc = *reinterpret_cast<const f32x4*>(&hst[lane * 4 + i * 256]);
#pragma unroll
      for (int q = 0; q < 4; ++q) {
        const float xq = xc[q], hq = hc[q];
        A_ir = fmaf(w4[ 0 + i][q], xq, A_ir);
        A_iz = fmaf(w4[ 4 + i][q], xq, A_iz);
        A_in = fmaf(w4[ 8 + i][q], xq, A_in);
        A_hr = fmaf(w4[12 + i][q], hq, A_hr);
        A_hz = fmaf(w4[16 + i][q], hq, A_hz);
        A_hn = fmaf(w4[20 + i][q], hq, A_hn);
        B_ir = fmaf(w4[24 + i][q], xq, B_ir);
        B_iz = fmaf(w4[28 + i][q], xq, B_iz);
        B_in = fmaf(w4[32 + i][q], xq, B_in);
        B_hr = fmaf(w4[36 + i][q], hq, B_hr);
        B_hz = fmaf(w4[40 + i][q], hq, B_hz);
        B_hn = fmaf(w4[44 + i][q], hq, B_hn);
      }
    }
    // r,z gates: ih+hh partials pre-added (8 butterflies instead of 12)
    float sAr = A_ir + A_hr, sAz = A_iz + A_hz;
    float sBr = B_ir + B_hr, sBz = B_iz + B_hz;
#pragma unroll
    for (int off = 32; off > 0; off >>= 1) {
      sAr  += __shfl_xor(sAr,  off, 64);
      sAz  += __shfl_xor(sAz,  off, 64);
      A_in += __shfl_xor(A_in, off, 64);
      A_hn += __shfl_xor(A_hn, off, 64);
      sBr  += __shfl_xor(sBr,  off, 64);
      sBz  += __shfl_xor(sBz,  off, 64);
      B_in += __shfl_xor(B_in, off, 64);
      B_hn += __shfl_xor(B_hn, off, 64);
    }

    // ---- gates; publish h / ring / out (sc1 write-through) ----
    const float rA = sigmoidf_(sAr + bA0);
    const float zA = sigmoidf_(sAz + bA1);
    const float nA = tanhf_(A_in + bA2 + rA * (A_hn + bnA));
    const float hA = nA + zA * (hregA - nA);
    const float rB = sigmoidf_(sBr + bB0);
    const float zB = sigmoidf_(sBz + bB1);
    const float nB = tanhf_(B_in + bB2 + rB * (B_hn + bnB));
    const float hB = nB + zB * (hregB - nB);
    hregA = hA; hregB = hB;

    if (lane == 0) {
      const unsigned long long pk =
          ((unsigned long long)__float_as_uint(hB) << 32) |
          (unsigned long long)__float_as_uint(hA);
      float* hdst = hb + (size_t)((t + 1) & 1) * HDIM + j0;
      asm volatile("global_store_dwordx2 %0, %1, off sc1"
                   :: "v"(hdst), "v"(pk) : "memory");
      float* xdst = (g < 3)
          ? ring_out + (size_t)(t & (RING - 1)) * HDIM + j0
          : p.out + (size_t)t * HDIM + j0;
      asm volatile("global_store_dwordx2 %0, %1, off sc1"
                   :: "v"(xdst), "v"(pk) : "memory");
    }
    // retire this wave's stores (acked at IF), then block-wide publish
    asm volatile("s_waitcnt vmcnt(0)" ::: "memory");
    __syncthreads();
    if (tid == 0)
      __hip_atomic_store(&p.tags[blk], t + 1,
                         __ATOMIC_RELAXED, __HIP_MEMORY_SCOPE_AGENT);
  }
}

extern "C" void kernel_launch(void* const* d_in, const int* in_sizes, int n_in,
                              void* d_out, int out_size, void* d_ws, size_t ws_size,
                              hipStream_t stream) {
  GruParams p;
  p.xs = (const float*)d_in[0];
  for (int l = 0; l < NLAYER; ++l) {
    p.Wih[l]  = (const float*)d_in[1 + 4 * l];
    p.Whh[l]  = (const float*)d_in[2 + 4 * l];
    p.bias[l] = (const float*)d_in[3 + 4 * l];
    p.bn[l]   = (const float*)d_in[4 + 4 * l];
  }
  char* ws = (char*)d_ws;
  size_t off = 0;
  p.tags = (int*)(ws + off);
  off += (size_t)NB * sizeof(int);
  off = (off + 255) & ~(size_t)255;
  p.hbuf = (float*)(ws + off);
  off += (size_t)NLAYER * 2 * HDIM * sizeof(float);
  p.ring = (float*)(ws + off);
  off += (size_t)3 * RING * HDIM * sizeof(float);
  p.out = (float*)d_out;

  (void)hipMemsetAsync(p.tags, 0, (size_t)NB * sizeof(int), stream);
  gru_pipe<<<dim3(NB), dim3(NT), 0, stream>>>(p);
}

// Round 8
// 39025.214 us; speedup vs baseline: 1.6239x; 1.1282x over previous
//
#include <hip/hip_runtime.h>

#define TSTEPS 8192
#define HDIM   1024
#define NLAYER 4
#define NB     256          // 4 groups x 64 blocks, persistent, 1 block/CU
#define NT     512          // 8 waves/block
#define GB     64           // blocks per group (per layer)
#define EPB    16           // h elements per block (2 per wave)
#define RING   16           // ring depth (layer boundary), pairs

typedef float    f32x4 __attribute__((ext_vector_type(4)));
typedef unsigned u32x4 __attribute__((ext_vector_type(4)));
typedef unsigned long long u64;

struct GruParams {
  const float* xs;
  const float* Wih[NLAYER];
  const float* Whh[NLAYER];
  const float* bias[NLAYER];
  const float* bn[NLAYER];
  float* out;      // d_out (written by group 3)
  int*   ctags;    // ws: NB per-block ring-consume tags
  u64*   hbp;      // ws: NLAYER * 2 * HDIM (value,epoch) pairs
  u64*   ringp;    // ws: 3 * RING * HDIM (value,epoch) pairs
};

__device__ __forceinline__ float sigmoidf_(float x) {
  return 1.0f / (1.0f + __expf(-x));
}
__device__ __forceinline__ float tanhf_(float x) {
  const float e = __expf(2.0f * x);
  return 1.0f - 2.0f / (e + 1.0f);
}
__device__ __forceinline__ float rfl_(float x) {
  return __int_as_float(__builtin_amdgcn_readfirstlane(__float_as_int(x)));
}

// Poll-gather one 1024-element row of (value,epoch) pairs (this lane's 16)
// until every epoch == e, then stage values into lds[0..1023].
// The gather IS the readiness check: one IF round-trip, no tags, no ack.
__device__ __forceinline__ void poll_stage_row_(const u64* buf, unsigned e,
                                                float* lds, int lane) {
  const u64* p0 = buf + lane * 4;
  u32x4 r0, r1, r2, r3, r4, r5, r6, r7;
  for (;;) {
    asm volatile(
        "global_load_dwordx4 %0, %8, off sc1\n\t"
        "global_load_dwordx4 %1, %9, off sc1\n\t"
        "global_load_dwordx4 %2, %10, off sc1\n\t"
        "global_load_dwordx4 %3, %11, off sc1\n\t"
        "global_load_dwordx4 %4, %12, off sc1\n\t"
        "global_load_dwordx4 %5, %13, off sc1\n\t"
        "global_load_dwordx4 %6, %14, off sc1\n\t"
        "global_load_dwordx4 %7, %15, off sc1\n\t"
        "s_waitcnt vmcnt(0)"
        : "=&v"(r0), "=&v"(r1), "=&v"(r2), "=&v"(r3),
          "=&v"(r4), "=&v"(r5), "=&v"(r6), "=&v"(r7)
        : "v"(p0), "v"(p0 + 2), "v"(p0 + 256), "v"(p0 + 258),
          "v"(p0 + 512), "v"(p0 + 514), "v"(p0 + 768), "v"(p0 + 770)
        : "memory");
    bool ok = (r0.y == e) & (r0.w == e) & (r1.y == e) & (r1.w == e) &
              (r2.y == e) & (r2.w == e) & (r3.y == e) & (r3.w == e) &
              (r4.y == e) & (r4.w == e) & (r5.y == e) & (r5.w == e) &
              (r6.y == e) & (r6.w == e) & (r7.y == e) & (r7.w == e);
    if (__all(ok)) break;
    __builtin_amdgcn_s_sleep(1);   // light backoff: cut IF poll storm
  }
  f32x4 v;
  v.x = __uint_as_float(r0.x); v.y = __uint_as_float(r0.z);
  v.z = __uint_as_float(r1.x); v.w = __uint_as_float(r1.z);
  *reinterpret_cast<f32x4*>(&lds[0 * 256 + lane * 4]) = v;
  v.x = __uint_as_float(r2.x); v.y = __uint_as_float(r2.z);
  v.z = __uint_as_float(r3.x); v.w = __uint_as_float(r3.z);
  *reinterpret_cast<f32x4*>(&lds[1 * 256 + lane * 4]) = v;
  v.x = __uint_as_float(r4.x); v.y = __uint_as_float(r4.z);
  v.z = __uint_as_float(r5.x); v.w = __uint_as_float(r5.z);
  *reinterpret_cast<f32x4*>(&lds[2 * 256 + lane * 4]) = v;
  v.x = __uint_as_float(r6.x); v.y = __uint_as_float(r6.z);
  v.z = __uint_as_float(r7.x); v.w = __uint_as_float(r7.z);
  *reinterpret_cast<f32x4*>(&lds[3 * 256 + lane * 4]) = v;
}

__device__ __forceinline__ void stage_plain_row_(const float* row, float* lds,
                                                 int lane) {
#pragma unroll
  for (int i = 0; i < 4; ++i)
    *reinterpret_cast<f32x4*>(&lds[i * 256 + lane * 4]) =
        *reinterpret_cast<const f32x4*>(row + i * 256 + lane * 4);
}

// Layer-pipelined persistent GRU, epoch-carrying dataflow, one barrier/tick.
// Wave roles per tick t (after everyone runs ih-FMAs on xst[t&1]):
//   wave0: poll+stage h(t) pairs -> hst[t&1]; set LDS hflag[t&1]=t.
//   wave1: prefetch x(t+1) (ring pairs / plain xs) -> xst[(t+1)&1]; ctag.
//   wave2: every 8th tick, ring-overwrite throttle on downstream ctags.
// Then all waves: spin LDS hflag, hh-FMAs, reduce, gates, pair-store h+ring.
__global__ __attribute__((amdgpu_flat_work_group_size(NT, NT),
                          amdgpu_waves_per_eu(2, 2)))
void gru_pipe(GruParams p) {
  __shared__ float xst[2][HDIM];
  __shared__ float hst[2][HDIM];
  __shared__ int hflag[2];
  const int tid  = threadIdx.x;
  const int lane = tid & 63;
  const int wave = tid >> 6;
  const int blk  = blockIdx.x;
  const int g    = blk >> 6;
  const int m    = blk & 63;
  const int j0   = m * EPB + wave * 2;

  // ---- weights: 12 rows (2 elems x (3 ih + 3 hh)) -> 48 f32x4 on-chip ----
  const float* Wih = p.Wih[g];
  const float* Whh = p.Whh[g];
  f32x4 w4[48];
#pragma unroll
  for (int e = 0; e < 2; ++e) {
#pragma unroll
    for (int dd = 0; dd < 6; ++dd) {
      const float* W = (dd < 3) ? Wih : Whh;
      const int gate = (dd < 3) ? dd : dd - 3;
      const float* src = W + ((size_t)gate * HDIM + (j0 + e)) * HDIM + lane * 4;
#pragma unroll
      for (int i = 0; i < 4; ++i)
        w4[(e * 6 + dd) * 4 + i] = *reinterpret_cast<const f32x4*>(src + i * 256);
    }
  }
  const float bA0 = rfl_(p.bias[g][j0]);
  const float bA1 = rfl_(p.bias[g][HDIM + j0]);
  const float bA2 = rfl_(p.bias[g][2 * HDIM + j0]);
  const float bnA = rfl_(p.bn[g][j0]);
  const float bB0 = rfl_(p.bias[g][j0 + 1]);
  const float bB1 = rfl_(p.bias[g][HDIM + j0 + 1]);
  const float bB2 = rfl_(p.bias[g][2 * HDIM + j0 + 1]);
  const float bnB = rfl_(p.bn[g][j0 + 1]);
  float hregA = 0.f, hregB = 0.f;

  u64* hp = p.hbp + (size_t)g * 2 * HDIM;
  const u64* ring_in  = p.ringp + (size_t)(g - 1) * RING * HDIM;  // g>0
  u64*       ring_out = p.ringp + (size_t)g * RING * HDIM;        // g<3

  // ---- prologue: flags, stage x(0) ----
  if (tid == 0) { hflag[0] = -1; hflag[1] = -1; }
  if (wave == 1) {
    if (g == 0)
      stage_plain_row_(p.xs, &xst[0][0], lane);
    else {
      poll_stage_row_(ring_in, 1u, &xst[0][0], lane);
      if (lane == 0)
        __hip_atomic_store(&p.ctags[blk], 1, __ATOMIC_RELAXED,
                           __HIP_MEMORY_SCOPE_AGENT);
    }
  }
  __syncthreads();

  for (int t = 0; t < TSTEPS; ++t) {
    const int par = t & 1;

    // ---- ih FMAs from xst[par] (h-independent; overlaps the h RT) ----
    float A_ir = 0.f, A_iz = 0.f, A_in = 0.f;
    float B_ir = 0.f, B_iz = 0.f, B_in = 0.f;
#pragma unroll
    for (int i = 0; i < 4; ++i) {
      const f32x4 v = *reinterpret_cast<const f32x4*>(&xst[par][i * 256 + lane * 4]);
#pragma unroll
      for (int q = 0; q < 4; ++q) {
        const float xq = v[q];
        A_ir = fmaf(w4[ 0 + i][q], xq, A_ir);
        A_iz = fmaf(w4[ 4 + i][q], xq, A_iz);
        A_in = fmaf(w4[ 8 + i][q], xq, A_in);
        B_ir = fmaf(w4[24 + i][q], xq, B_ir);
        B_iz = fmaf(w4[28 + i][q], xq, B_iz);
        B_in = fmaf(w4[32 + i][q], xq, B_in);
      }
    }

    // ---- wave role tasks ----
    if (wave == 0) {
      if (t > 0) {
        poll_stage_row_(hp + (size_t)par * HDIM, (unsigned)t, &hst[par][0], lane);
        asm volatile("s_waitcnt lgkmcnt(0)" ::: "memory");  // data before flag
        if (lane == 0) ((volatile int*)hflag)[par] = t;
      }
    } else if (wave == 1) {
      if (t + 1 < TSTEPS) {
        const int pn = (t + 1) & 1;
        if (g == 0)
          stage_plain_row_(p.xs + (size_t)(t + 1) * HDIM, &xst[pn][0], lane);
        else {
          poll_stage_row_(ring_in + (size_t)((t + 1) & (RING - 1)) * HDIM,
                          (unsigned)(t + 2), &xst[pn][0], lane);
          if (lane == 0)
            __hip_atomic_store(&p.ctags[blk], t + 2, __ATOMIC_RELAXED,
                               __HIP_MEMORY_SCOPE_AGENT);
        }
      }
    } else if (wave == 2) {
      // ring-overwrite throttle: every 8 ticks, >=8-tick slack (RING=16)
      if (g < 3 && t >= RING && (t & 7) == 0) {
        const int bound = t - 8;
        const int* tp = p.ctags + (g + 1) * GB + lane;
        for (;;) {
          const int v = __hip_atomic_load(tp, __ATOMIC_RELAXED,
                                          __HIP_MEMORY_SCOPE_AGENT);
          if (__all(v >= bound)) break;
          __builtin_amdgcn_s_sleep(4);
        }
      }
    }

    // ---- wait h ready (LDS flag, no IF traffic); hh FMAs ----
    float A_hr = 0.f, A_hz = 0.f, A_hn = 0.f;
    float B_hr = 0.f, B_hz = 0.f, B_hn = 0.f;
    if (t > 0) {
      if (wave != 0) {
        while (((volatile int*)hflag)[par] != t) { }
        asm volatile("s_waitcnt lgkmcnt(0)" ::: "memory");
        __builtin_amdgcn_sched_barrier(0);
      }
#pragma unroll
      for (int i = 0; i < 4; ++i) {
        const f32x4 v = *reinterpret_cast<const f32x4*>(&hst[par][i * 256 + lane * 4]);
#pragma unroll
        for (int q = 0; q < 4; ++q) {
          const float hq = v[q];
          A_hr = fmaf(w4[12 + i][q], hq, A_hr);
          A_hz = fmaf(w4[16 + i][q], hq, A_hz);
          A_hn = fmaf(w4[20 + i][q], hq, A_hn);
          B_hr = fmaf(w4[36 + i][q], hq, B_hr);
          B_hz = fmaf(w4[40 + i][q], hq, B_hz);
          B_hn = fmaf(w4[44 + i][q], hq, B_hn);
        }
      }
    }

    // ---- reduce (r,z pre-added) + gates ----
    float sAr = A_ir + A_hr, sAz = A_iz + A_hz;
    float sBr = B_ir + B_hr, sBz = B_iz + B_hz;
#pragma unroll
    for (int off = 32; off > 0; off >>= 1) {
      sAr  += __shfl_xor(sAr,  off, 64);
      sAz  += __shfl_xor(sAz,  off, 64);
      A_in += __shfl_xor(A_in, off, 64);
      A_hn += __shfl_xor(A_hn, off, 64);
      sBr  += __shfl_xor(sBr,  off, 64);
      sBz  += __shfl_xor(sBz,  off, 64);
      B_in += __shfl_xor(B_in, off, 64);
      B_hn += __shfl_xor(B_hn, off, 64);
    }
    const float rA = sigmoidf_(sAr + bA0);
    const float zA = sigmoidf_(sAz + bA1);
    const float nA = tanhf_(A_in + bA2 + rA * (A_hn + bnA));
    const float hA = nA + zA * (hregA - nA);
    const float rB = sigmoidf_(sBr + bB0);
    const float zB = sigmoidf_(sBz + bB1);
    const float nB = tanhf_(B_in + bB2 + rB * (B_hn + bnB));
    const float hB = nB + zB * (hregB - nB);
    hregA = hA; hregB = hB;

    // ---- publish: epoch-carrying pair stores, fire-and-forget ----
    if (lane == 0) {
      u32x4 pk;
      pk.x = __float_as_uint(hA); pk.y = (unsigned)(t + 1);
      pk.z = __float_as_uint(hB); pk.w = (unsigned)(t + 1);
      u64* hdst = hp + (size_t)((t + 1) & 1) * HDIM + j0;
      asm volatile("global_store_dwordx4 %0, %1, off sc1"
                   :: "v"(hdst), "v"(pk) : "memory");
      if (g < 3) {
        u64* rdst = ring_out + (size_t)(t & (RING - 1)) * HDIM + j0;
        asm volatile("global_store_dwordx4 %0, %1, off sc1"
                     :: "v"(rdst), "v"(pk) : "memory");
      } else {
        const u64 po = ((u64)__float_as_uint(hB) << 32) |
                       (u64)__float_as_uint(hA);
        float* od = p.out + (size_t)t * HDIM + j0;
        asm volatile("global_store_dwordx2 %0, %1, off sc1"
                     :: "v"(od), "v"(po) : "memory");
      }
    }
    // one barrier/tick: protects xst/hst parity buffers + hflag reuse
    __syncthreads();
  }
}

extern "C" void kernel_launch(void* const* d_in, const int* in_sizes, int n_in,
                              void* d_out, int out_size, void* d_ws, size_t ws_size,
                              hipStream_t stream) {
  GruParams p;
  p.xs = (const float*)d_in[0];
  for (int l = 0; l < NLAYER; ++l) {
    p.Wih[l]  = (const float*)d_in[1 + 4 * l];
    p.Whh[l]  = (const float*)d_in[2 + 4 * l];
    p.bias[l] = (const float*)d_in[3 + 4 * l];
    p.bn[l]   = (const float*)d_in[4 + 4 * l];
  }
  char* ws = (char*)d_ws;
  size_t off = 0;
  p.ctags = (int*)(ws + off);
  off += (size_t)NB * sizeof(int);
  off = (off + 255) & ~(size_t)255;
  p.hbp = (u64*)(ws + off);
  const size_t hbp_bytes = (size_t)NLAYER * 2 * HDIM * sizeof(u64);
  off += hbp_bytes;
  p.ringp = (u64*)(ws + off);
  const size_t ring_bytes = (size_t)3 * RING * HDIM * sizeof(u64);
  off += ring_bytes;
  p.out = (float*)d_out;

  // Replay safety: epochs restart at 1 each launch -> stale epochs from a
  // previous replay would deadlock/corrupt. Clear ALL epoch-bearing state.
  (void)hipMemsetAsync(p.ctags, 0, (size_t)NB * sizeof(int), stream);
  (void)hipMemsetAsync(p.hbp, 0, hbp_bytes, stream);
  (void)hipMemsetAsync(p.ringp, 0, ring_bytes, stream);
  gru_pipe<<<dim3(NB), dim3(NT), 0, stream>>>(p);
}